// Round 1
// baseline (412.739 us; speedup 1.0000x reference)
//
#include <hip/hip_runtime.h>
#include <hip/hip_fp16.h>
#include <math.h>

#define DEPTH 6
#define HEADS 8
#define BB    2
#define NN    128
#define EE    160
#define NF    127
#define DIMM  128
#define INNER 512
#define NNODE 256
#define NBLK  256

typedef _Float16 h2f16 __attribute__((ext_vector_type(2)));

#if defined(__has_builtin)
#if __has_builtin(__builtin_amdgcn_fdot2)
#define HAVE_FDOT2 1
#endif
#endif

__device__ __forceinline__ float fdot2f(h2f16 a, h2f16 b, float c) {
#ifdef HAVE_FDOT2
    return __builtin_amdgcn_fdot2(a, b, c, false);
#else
    return c + (float)a.x * (float)b.x + (float)a.y * (float)b.y;
#endif
}

__device__ __forceinline__ void gload16(const void* g, void* l) {
    __builtin_amdgcn_global_load_lds((const __attribute__((address_space(1))) void*)g,
                                     (__attribute__((address_space(3))) void*)l,
                                     16, 0, 0);
}

// wait this wave's outstanding vmem (vmcnt(0); lgkm/exp unconstrained)
__device__ __forceinline__ void wait_vm0() { __builtin_amdgcn_s_waitcnt(0x0f70); }
// drain this wave's LDS ops before slice overwrite
__device__ __forceinline__ void wait_lgkm0() { __builtin_amdgcn_s_waitcnt(0xC07F); }

// Per-wave 16 KB contiguous stage: 16 x (1 KB gload16). ldsslice wave-uniform.
__device__ __forceinline__ void wstage16(const char* gslice, char* ldsslice, int ln) {
#pragma unroll
    for (int i = 0; i < 16; i++)
        gload16(gslice + i * 1024 + ln * 16, ldsslice + i * 1024);
}
// Strided variant: 16 rows of 1 KB, global row stride `rowstride` bytes.
__device__ __forceinline__ void wstage16s(const char* gslice, int rowstride,
                                          char* ldsslice, int ln) {
#pragma unroll
    for (int i = 0; i < 16; i++)
        gload16(gslice + (size_t)i * rowstride + ln * 16, ldsslice + i * 1024);
}

__device__ __forceinline__ void fma8h(float4& a0, float4& a1, float s, float4 raw) {
    const __half2* hp = (const __half2*)&raw;
    float2 p0 = __half22float2(hp[0]), p1 = __half22float2(hp[1]);
    float2 p2 = __half22float2(hp[2]), p3 = __half22float2(hp[3]);
    a0.x += s * p0.x; a0.y += s * p0.y; a0.z += s * p1.x; a0.w += s * p1.y;
    a1.x += s * p2.x; a1.y += s * p2.y; a1.z += s * p3.x; a1.w += s * p3.y;
}

// GEMV unit, C=512 K=128, wave w owns rows [w*16, w*16+16). wbuf = 16 rows x 1KB.
__device__ __forceinline__ void gemv512(const float* act, const float* wbuf,
                                        float* s_part, int w, int ln) {
    float4 a0 = {0,0,0,0}, a1 = {0,0,0,0};
    const float4* w4 = (const float4*)wbuf;
#pragma unroll
    for (int r = 0; r < 16; r++)
        fma8h(a0, a1, act[w * 16 + r], w4[r * 64 + ln]);
    ((float4*)(s_part + w * 512))[ln * 2]     = a0;
    ((float4*)(s_part + w * 512))[ln * 2 + 1] = a1;
}

// GEMV unit, C=128 K=512, wave w owns rows [w*64, w*64+64). wbuf = 64 rows x 256B.
__device__ __forceinline__ void gemv128(const float* act, const float* wbuf,
                                        float* s_part, int w, int ln) {
    float2 acc = {0, 0};
#pragma unroll 8
    for (int r = 0; r < 64; r++) {
        float raw = wbuf[r * 64 + ln];
        float2 p = __half22float2(*(const __half2*)&raw);
        float a = act[w * 64 + r];
        acc.x += a * p.x; acc.y += a * p.y;
    }
    s_part[w * 128 + ln * 2]     = acc.x;
    s_part[w * 128 + ln * 2 + 1] = acc.y;
}

// N-value block reduce (8 waves); results broadcast into vals[].
template <int N>
__device__ __forceinline__ void block_reduce_n(float* vals, float* sbuf) {
#pragma unroll
    for (int off = 32; off > 0; off >>= 1)
#pragma unroll
        for (int q = 0; q < N; q++) vals[q] += __shfl_xor(vals[q], off, 64);
    int wave = threadIdx.x >> 6;
    if ((threadIdx.x & 63) == 0)
#pragma unroll
        for (int q = 0; q < N; q++) sbuf[wave * N + q] = vals[q];
    __syncthreads();
#pragma unroll
    for (int q = 0; q < N; q++) {
        float r = 0.0f;
#pragma unroll
        for (int g = 0; g < 8; g++) r += sbuf[g * N + q];
        vals[q] = r;
    }
    __syncthreads();
}

__device__ __forceinline__ float gelu_exact(float a) {
    return 0.5f * a * (1.0f + erff(a * 0.70710678f));
}

// Device-wide sense-reversing barrier. Safe: 158KB LDS forces 1 block/CU and
// grid == 256 == CU count, so all blocks are co-resident by construction.
__device__ __forceinline__ void gridbar(unsigned* bar) {
    __syncthreads();          // all waves drain vmem/lds (incl. hk/hv stores -> L2)
    if (threadIdx.x == 0) {
        __threadfence();      // device-scope release: L2 -> LLC visible cross-XCD
        unsigned g = __hip_atomic_load(&bar[1], __ATOMIC_RELAXED, __HIP_MEMORY_SCOPE_AGENT);
        unsigned a = __hip_atomic_fetch_add(&bar[0], 1u, __ATOMIC_ACQ_REL, __HIP_MEMORY_SCOPE_AGENT);
        if (a == NBLK - 1) {
            __hip_atomic_store(&bar[0], 0u, __ATOMIC_RELAXED, __HIP_MEMORY_SCOPE_AGENT);
            __hip_atomic_fetch_add(&bar[1], 1u, __ATOMIC_RELEASE, __HIP_MEMORY_SCOPE_AGENT);
        } else {
            while (__hip_atomic_load(&bar[1], __ATOMIC_ACQUIRE, __HIP_MEMORY_SCOPE_AGENT) == g)
                __builtin_amdgcn_s_sleep(2);
        }
        __threadfence();      // acquire side
    }
    __syncthreads();
}

// ---------- kernels ----------

__global__ __launch_bounds__(512) void k_cvt(const float* Wq, const float* Wkv,
                                             const float* Wo, const float* W1,
                                             const float* W2,
                                             __half* hWq, __half* hWkv, __half* hWo,
                                             __half* hW1, __half* hW2,
                                             const float* blin, float* out,
                                             unsigned* bar) {
    if (blockIdx.x == 0 && threadIdx.x == 0) {
        out[0] = 256.0f * blin[0];
        bar[0] = 0u;
        bar[1] = 0u;
    }
    int g = blockIdx.x * 512 + threadIdx.x;
    const float4* src; __half* dst; int off;
    if (g < 98304)       { src = (const float4*)Wq;  dst = hWq;  off = g; }
    else if (g < 294912) { src = (const float4*)Wkv; dst = hWkv; off = g - 98304; }
    else if (g < 393216) { src = (const float4*)Wo;  dst = hWo;  off = g - 294912; }
    else if (g < 491520) { src = (const float4*)W1;  dst = hW1;  off = g - 393216; }
    else                 { src = (const float4*)W2;  dst = hW2;  off = g - 491520; }
    float4 v = src[off];
    __half2* d2 = (__half2*)(dst + (size_t)off * 4);
    d2[0] = __floats2half2_rn(v.x, v.y);
    d2[1] = __floats2half2_rn(v.z, v.w);
}

// Shared tail: Wq -> s_q, Wk -> hkrow, Wv -> hvrow; stages next Wo before return
// so the DMA spans the following grid barrier. Wq slice must already be staged.
__device__ __forceinline__ void qkv_phase(const float* s_xn, float* s_part, float* s_q,
                                          char* lslice, float* wbuf,
                                          const char* WkvL, const char* WoNextL,
                                          const float* bq_l, const float* bkv_l,
                                          __half* hkrow, __half* hvrow,
                                          int w, int ln, int t) {
    // Wq
    wait_vm0();
    gemv512(s_xn, wbuf, s_part, w, ln);
    wait_lgkm0();
    wstage16s(WkvL + (size_t)(w * 16) * 2048, 2048, lslice, ln);   // Wk
    __syncthreads();
    {
        float q = bq_l[t];
#pragma unroll
        for (int g = 0; g < 8; g++) q += s_part[g * 512 + t];
        s_q[t] = q;
    }
    __syncthreads();

    // Wk
    wait_vm0();
    gemv512(s_xn, wbuf, s_part, w, ln);
    wait_lgkm0();
    wstage16s(WkvL + (size_t)(w * 16) * 2048 + 1024, 2048, lslice, ln);   // Wv
    __syncthreads();
    {
        float k = bkv_l[t];
#pragma unroll
        for (int g = 0; g < 8; g++) k += s_part[g * 512 + t];
        hkrow[t] = __float2half(k);
    }
    __syncthreads();

    // Wv
    wait_vm0();
    gemv512(s_xn, wbuf, s_part, w, ln);
    wait_lgkm0();
    wstage16(WoNextL + w * 16384, lslice, ln);   // next-layer Wo; flies over barrier
    __syncthreads();
    {
        float v = bkv_l[INNER + t];
#pragma unroll
        for (int g = 0; g < 8; g++) v += s_part[g * 512 + t];
        hvrow[t] = __float2half(v);
    }
}

__global__ __launch_bounds__(512, 1) void k_net(
        const int* indices, const float* coords, const int* bonds, const float* noise,
        const float* atom_emb, const float* ln1_g, const float* ln1_b,
        const __half* hWq, const float* bq, const __half* hWkv, const float* bkv,
        const float* We, const float* be,
        const __half* hWo, const float* bo, const float* Wg1,
        const float* ln2_g, const float* ln2_b,
        const __half* hW1, const float* b1, const __half* hW2, const float* b2,
        const float* Wg2, const float* Wlin, float* out,
        __half* hkb, __half* hvb, unsigned* bar) {
    int bn = blockIdx.x;
    int b = bn >> 7, i = bn & 127;
    int t = threadIdx.x;
    int d = t & 127;
    bool own = (t < 128);
    int w = t >> 6, ln = t & 63;

    __shared__ float arena[32768];     // per-wave weight slices (16 KB each)
    __shared__ float scoord[384];
    __shared__ float sedge[384];
    __shared__ int   sadj[128];
    __shared__ float s_l[64];
    __shared__ float s_ao[512];
    __shared__ float s_h[512];
    __shared__ float s_xn[128];
    __shared__ float s_red[48];
    __shared__ float s_part[4096];     // aliased as s_o in attention
    __shared__ float s_q[512];
    float* s_o = s_part;
    char*  lslice = (char*)arena + w * 16384;
    float* wbuf   = arena + w * 4096;

    // stage Wq(layer 0) immediately; DMA overlaps the whole setup below
    wstage16((const char*)hWq + w * 16384, lslice, ln);

    // ---------- one-time setup: coords, adjacency, masked edge vectors ----------
    if (t < 3 * NN) scoord[t] = coords[b * 3 * NN + t];
    if (t < NN) sadj[t] = 0;
    __syncthreads();
    if (t < EE) {
        int e0 = bonds[2 * t], e1 = bonds[2 * t + 1];
        if (e0 == i) sadj[e1] = 1;
        if (e1 == i) sadj[e0] = 1;
    }
    __syncthreads();
    if (t < NN) {
        int j = t;
        float msk = sadj[j] ? 1.0f : 0.0f;
        sedge[3 * j + 0] = msk * (scoord[3 * i + 0] - scoord[3 * j + 0]);
        sedge[3 * j + 1] = msk * (scoord[3 * i + 1] - scoord[3 * j + 1]);
        sedge[3 * j + 2] = msk * (scoord[3 * i + 2] - scoord[3 * j + 2]);
    }

    // ---------- gather + LN1(0); res carried in a register all 6 layers ----------
    float res = 0.0f;
    if (own) {
        int idx = indices[bn];
        res = (d < NF) ? atom_emb[idx * NF + d] : noise[0];
    }
    {
        float vals[2] = {own ? res : 0.0f, own ? res * res : 0.0f};
        block_reduce_n<2>(vals, s_red);   // first sync also covers sedge writes
        float m   = vals[0] * (1.0f / 128.0f);
        float var = vals[1] * (1.0f / 128.0f) - m * m;
        if (own) s_xn[d] = (res - m) * rsqrtf(var + 1e-5f) * ln1_g[d] + ln1_b[d];
    }
    __syncthreads();

    qkv_phase(s_xn, s_part, s_q, lslice, wbuf,
              (const char*)hWkv, (const char*)hWo, bq, bkv,
              hkb + (size_t)bn * INNER, hvb + (size_t)bn * INNER, w, ln, t);
    gridbar(bar);

    for (int l = 0; l < DEPTH; l++) {
        const float4* kR = (const float4*)(hkb + (size_t)(l & 1) * NNODE * INNER
                                               + (size_t)b * NN * INNER);
        const float4* vR = (const float4*)(hvb + (size_t)(l & 1) * NNODE * INNER
                                               + (size_t)b * NN * INNER);
        const float4* WeR = (const float4*)(We + (size_t)l * 3 * INNER);
        const float4* beR = (const float4*)(be + (size_t)l * INNER);

        // ---------- attention: wave w owns j in [w*16, w*16+16) ----------
        float4 qa = ((const float4*)s_q)[ln * 2], qz = ((const float4*)s_q)[ln * 2 + 1];
        float4 w0a = WeR[ln * 2],       w0z = WeR[ln * 2 + 1];
        float4 w1a = WeR[128 + ln * 2], w1z = WeR[129 + ln * 2];
        float4 w2a = WeR[256 + ln * 2], w2z = WeR[257 + ln * 2];
        float4 bea = beR[ln * 2],       bez = beR[ln * 2 + 1];
        h2f16 qh0 = {(_Float16)qa.x, (_Float16)qa.y};
        h2f16 qh1 = {(_Float16)qa.z, (_Float16)qa.w};
        h2f16 qh2 = {(_Float16)qz.x, (_Float16)qz.y};
        h2f16 qh3 = {(_Float16)qz.z, (_Float16)qz.w};
        // per-head q.be (non-bonded j have e == be exactly)
        float c = qa.x * bea.x + qa.y * bea.y + qa.z * bea.z + qa.w * bea.w
                + qz.x * bez.x + qz.y * bez.y + qz.z * bez.z + qz.w * bez.w;
        c += __shfl_xor(c, 1, 64); c += __shfl_xor(c, 2, 64); c += __shfl_xor(c, 4, 64);

        float l_run = 0.0f, S_nb = 0.0f;
        float4 o0 = {0, 0, 0, 0}, o1 = {0, 0, 0, 0};
        int j0 = w * 16;
#pragma unroll
        for (int base = 0; base < 16; base += 4) {
            float4 kraw[4], vraw[4];
#pragma unroll
            for (int p = 0; p < 4; p++) {
                int j = j0 + base + p;
                kraw[p] = kR[j * 64 + ln];
                vraw[p] = vR[j * 64 + ln];
            }
#pragma unroll
            for (int p = 0; p < 4; p++) {
                int j = j0 + base + p;
                const h2f16* kh = (const h2f16*)&kraw[p];
                float s = fdot2f(qh0, kh[0],
                          fdot2f(qh1, kh[1],
                          fdot2f(qh2, kh[2],
                          fdot2f(qh3, kh[3], 0.0f))));
                bool bonded = (sadj[j] != 0);      // wave-uniform branch
                float4 e0, e1;
                if (bonded) {
                    float ex = sedge[3 * j], ey = sedge[3 * j + 1], ez = sedge[3 * j + 2];
                    e0.x = bea.x + ex * w0a.x + ey * w1a.x + ez * w2a.x;
                    e0.y = bea.y + ex * w0a.y + ey * w1a.y + ez * w2a.y;
                    e0.z = bea.z + ex * w0a.z + ey * w1a.z + ez * w2a.z;
                    e0.w = bea.w + ex * w0a.w + ey * w1a.w + ez * w2a.w;
                    e1.x = bez.x + ex * w0z.x + ey * w1z.x + ez * w2z.x;
                    e1.y = bez.y + ex * w0z.y + ey * w1z.y + ez * w2z.y;
                    e1.z = bez.z + ex * w0z.z + ey * w1z.z + ez * w2z.z;
                    e1.w = bez.w + ex * w0z.w + ey * w1z.w + ez * w2z.w;
                    s += qa.x * e0.x + qa.y * e0.y + qa.z * e0.z + qa.w * e0.w
                       + qz.x * e1.x + qz.y * e1.y + qz.z * e1.z + qz.w * e1.w;
                }
                s += __shfl_xor(s, 1, 64);
                s += __shfl_xor(s, 2, 64);
                s += __shfl_xor(s, 4, 64);
                if (!bonded) s += c;
                float pp = __expf(s * 0.125f);
                l_run += pp;
                const __half2* vh = (const __half2*)&vraw[p];
                float2 v0 = __half22float2(vh[0]), v1 = __half22float2(vh[1]);
                float2 v2 = __half22float2(vh[2]), v3 = __half22float2(vh[3]);
                o0.x += pp * v0.x; o0.y += pp * v0.y; o0.z += pp * v1.x; o0.w += pp * v1.y;
                o1.x += pp * v2.x; o1.y += pp * v2.y; o1.z += pp * v3.x; o1.w += pp * v3.y;
                if (bonded) {
                    o0.x += pp * e0.x; o0.y += pp * e0.y; o0.z += pp * e0.z; o0.w += pp * e0.w;
                    o1.x += pp * e1.x; o1.y += pp * e1.y; o1.z += pp * e1.z; o1.w += pp * e1.w;
                } else S_nb += pp;
            }
        }
        // fold the shared be contribution of all non-bonded j
        o0.x += S_nb * bea.x; o0.y += S_nb * bea.y; o0.z += S_nb * bea.z; o0.w += S_nb * bea.w;
        o1.x += S_nb * bez.x; o1.y += S_nb * bez.y; o1.z += S_nb * bez.z; o1.w += S_nb * bez.w;
        ((float4*)(s_o + w * 512))[ln * 2]     = o0;
        ((float4*)(s_o + w * 512))[ln * 2 + 1] = o1;
        if ((ln & 7) == 0) s_l[w * 8 + (ln >> 3)] = l_run;
        __syncthreads();
        {
            float o = 0.0f;
#pragma unroll
            for (int g = 0; g < 8; g++) o += s_o[g * 512 + t];
            int h = t >> 6;
            float lsum = 0.0f;
#pragma unroll
            for (int g = 0; g < 8; g++) lsum += s_l[g * 8 + h];
            s_ao[t] = o / lsum;
        }
        __syncthreads();

        // ---------- Wo [512 x 128], K-split ----------
        wait_vm0();
        gemv128(s_ao, wbuf, s_part, w, ln);
        wait_lgkm0();
        wstage16((const char*)hW1 + (size_t)l * 131072 + w * 16384, lslice, ln);
        __syncthreads();
        float x = 0.0f;
        if (own) {
            x = bo[l * DIMM + d];
#pragma unroll
            for (int g = 0; g < 8; g++) x += s_part[g * 128 + d];
        }

        // ---------- fused gate1 + LN2 ----------
        const float* Wg1_l = Wg1 + l * 3 * DIMM;
        float n1;
        {
            float tex = own ? (x * Wg1_l[d] + res * Wg1_l[DIMM + d]
                               + (x - res) * Wg1_l[2 * DIMM + d]) : 0.0f;
            float vals[6] = {tex,
                             own ? x : 0.0f, own ? x * x : 0.0f,
                             own ? x * res : 0.0f,
                             own ? res : 0.0f, own ? res * res : 0.0f};
            block_reduce_n<6>(vals, s_red);
            float g1 = 1.0f / (1.0f + __expf(-vals[0]));
            float sn  = g1 * vals[1] + (1.0f - g1) * vals[4];
            float sn2 = g1 * g1 * vals[2] + 2.0f * g1 * (1.0f - g1) * vals[3]
                      + (1.0f - g1) * (1.0f - g1) * vals[5];
            float m   = sn * (1.0f / 128.0f);
            float var = sn2 * (1.0f / 128.0f) - m * m;
            n1 = x * g1 + res * (1.0f - g1);
            if (own) s_xn[d] = (n1 - m) * rsqrtf(var + 1e-5f) * ln2_g[l * DIMM + d]
                             + ln2_b[l * DIMM + d];
        }
        __syncthreads();

        // ---------- W1 [128 x 512] + gelu ----------
        wait_vm0();
        gemv512(s_xn, wbuf, s_part, w, ln);
        wait_lgkm0();
        wstage16((const char*)hW2 + (size_t)l * 131072 + w * 16384, lslice, ln);
        __syncthreads();
        {
            float a = b1[l * 4 * DIMM + t];
#pragma unroll
            for (int g = 0; g < 8; g++) a += s_part[g * 512 + t];
            s_h[t] = gelu_exact(a);
        }
        __syncthreads();

        // ---------- W2 [512 x 128], K-split ----------
        wait_vm0();
        gemv128(s_h, wbuf, s_part, w, ln);
        wait_lgkm0();
        if (l < DEPTH - 1)
            wstage16((const char*)hWq + (size_t)(l + 1) * 131072 + w * 16384, lslice, ln);
        __syncthreads();
        float y = 0.0f;
        if (own) {
            y = b2[l * DIMM + d];
#pragma unroll
            for (int g = 0; g < 8; g++) y += s_part[g * 128 + d];
        }

        const float* Wg2_l = Wg2 + l * 3 * DIMM;
        if (l < DEPTH - 1) {
            // ---------- fused gate2 + LN1' ----------
            float tex = own ? (y * Wg2_l[d] + n1 * Wg2_l[DIMM + d]
                               + (y - n1) * Wg2_l[2 * DIMM + d]) : 0.0f;
            float vals[6] = {tex,
                             own ? y : 0.0f, own ? y * y : 0.0f,
                             own ? y * n1 : 0.0f,
                             own ? n1 : 0.0f, own ? n1 * n1 : 0.0f};
            block_reduce_n<6>(vals, s_red);
            float g2 = 1.0f / (1.0f + __expf(-vals[0]));
            float sn  = g2 * vals[1] + (1.0f - g2) * vals[4];
            float sn2 = g2 * g2 * vals[2] + 2.0f * g2 * (1.0f - g2) * vals[3]
                      + (1.0f - g2) * (1.0f - g2) * vals[5];
            float m   = sn * (1.0f / 128.0f);
            float var = sn2 * (1.0f / 128.0f) - m * m;
            float n2 = y * g2 + n1 * (1.0f - g2);
            res = n2;   // carried in-register into next layer
            if (own) s_xn[d] = (n2 - m) * rsqrtf(var + 1e-5f) * ln1_g[(l + 1) * DIMM + d]
                             + ln1_b[(l + 1) * DIMM + d];
            __syncthreads();

            qkv_phase(s_xn, s_part, s_q, lslice, wbuf,
                      (const char*)hWkv + (size_t)(l + 1) * 262144,
                      (const char*)hWo + (size_t)(l + 1) * 131072,
                      bq + (size_t)(l + 1) * INNER, bkv + (size_t)(l + 1) * 2 * INNER,
                      hkb + (size_t)((l + 1) & 1) * NNODE * INNER + (size_t)bn * INNER,
                      hvb + (size_t)((l + 1) & 1) * NNODE * INNER + (size_t)bn * INNER,
                      w, ln, t);
            gridbar(bar);
        } else {
            // ---------- fused gate2 + final contribution ----------
            float wl = own ? Wlin[d] : 0.0f;
            float tex = own ? (y * Wg2_l[d] + n1 * Wg2_l[DIMM + d]
                               + (y - n1) * Wg2_l[2 * DIMM + d]) : 0.0f;
            float vals[3] = {tex, y * wl, n1 * wl};
            block_reduce_n<3>(vals, s_red);
            float g2 = 1.0f / (1.0f + __expf(-vals[0]));
            float tot = g2 * vals[1] + (1.0f - g2) * vals[2];
            if (t == 0) atomicAdd(out, tot);
        }
    }
}

extern "C" void kernel_launch(void* const* d_in, const int* in_sizes, int n_in,
                              void* d_out, int out_size, void* d_ws, size_t ws_size,
                              hipStream_t stream) {
    const int*   indices = (const int*)d_in[0];
    const float* coords  = (const float*)d_in[1];
    const int*   bonds   = (const int*)d_in[2];
    const float* noise   = (const float*)d_in[3];
    const float* atom_emb= (const float*)d_in[4];
    const float* ln1_g   = (const float*)d_in[5];
    const float* ln1_b   = (const float*)d_in[6];
    const float* Wq      = (const float*)d_in[7];
    const float* bq      = (const float*)d_in[8];
    const float* Wkv     = (const float*)d_in[9];
    const float* bkv     = (const float*)d_in[10];
    const float* We      = (const float*)d_in[11];
    const float* be      = (const float*)d_in[12];
    const float* Wo      = (const float*)d_in[13];
    const float* bo      = (const float*)d_in[14];
    const float* Wg1     = (const float*)d_in[15];
    const float* ln2_g   = (const float*)d_in[16];
    const float* ln2_b   = (const float*)d_in[17];
    const float* W1      = (const float*)d_in[18];
    const float* b1      = (const float*)d_in[19];
    const float* W2      = (const float*)d_in[20];
    const float* b2      = (const float*)d_in[21];
    const float* Wg2     = (const float*)d_in[22];
    const float* Wlin    = (const float*)d_in[23];
    const float* blin    = (const float*)d_in[24];

    float*    ws  = (float*)d_ws;
    unsigned* bar = (unsigned*)ws;                      // 2 uints, padded to 64 B
    __half* hkb  = (__half*)(ws + 16);                  // 2 slabs x NNODE*INNER
    __half* hvb  = hkb + 2 * NNODE * INNER;
    __half* hWq  = hvb + 2 * NNODE * INNER;
    __half* hWkv = hWq + DEPTH * DIMM * INNER;
    __half* hWo  = hWkv + DEPTH * DIMM * 2 * INNER;
    __half* hW1  = hWo + DEPTH * INNER * DIMM;
    __half* hW2  = hW1 + DEPTH * DIMM * 4 * DIMM;

    k_cvt<<<1152, 512, 0, stream>>>(Wq, Wkv, Wo, W1, W2, hWq, hWkv, hWo, hW1, hW2,
                                    blin, (float*)d_out, bar);
    k_net<<<NBLK, 512, 0, stream>>>(indices, coords, bonds, noise, atom_emb,
                                    ln1_g, ln1_b, hWq, bq, hWkv, bkv, We, be,
                                    hWo, bo, Wg1, ln2_g, ln2_b, hW1, b1, hW2, b2,
                                    Wg2, Wlin, (float*)d_out, hkb, hvb, bar);
}

// Round 2
// 259.632 us; speedup vs baseline: 1.5897x; 1.5897x over previous
//
#include <hip/hip_runtime.h>
#include <hip/hip_fp16.h>
#include <math.h>

#define DEPTH 6
#define HEADS 8
#define BB    2
#define NN    128
#define EE    160
#define NF    127
#define DIMM  128
#define INNER 512
#define NNODE 256

typedef _Float16 h2f16 __attribute__((ext_vector_type(2)));

#if defined(__has_builtin)
#if __has_builtin(__builtin_amdgcn_fdot2)
#define HAVE_FDOT2 1
#endif
#endif

__device__ __forceinline__ float fdot2f(h2f16 a, h2f16 b, float c) {
#ifdef HAVE_FDOT2
    return __builtin_amdgcn_fdot2(a, b, c, false);
#else
    return c + (float)a.x * (float)b.x + (float)a.y * (float)b.y;
#endif
}

__device__ __forceinline__ void gload16(const void* g, void* l) {
    __builtin_amdgcn_global_load_lds((const __attribute__((address_space(1))) void*)g,
                                     (__attribute__((address_space(3))) void*)l,
                                     16, 0, 0);
}

// s_waitcnt: vmcnt<=N, exp/lgkm unconstrained. gfx9 encoding:
// vmcnt[3:0]=bits3:0, exp=bits6:4, lgkm=bits11:8, vmcnt[5:4]=bits15:14.
template <int N>
__device__ __forceinline__ void wait_vm() {
    __builtin_amdgcn_s_waitcnt((0xF << 8) | (7 << 4) | (N & 0xF) | ((N >> 4) << 14));
}
// drain this wave's LDS ops before slice overwrite
__device__ __forceinline__ void wait_lgkm0() { __builtin_amdgcn_s_waitcnt(0xC07F); }
__device__ __forceinline__ void sbar0() { __builtin_amdgcn_sched_barrier(0); }

// Stage 8 rows of 1 KB (8 KB half-chunk); global row stride `rowstride` bytes.
__device__ __forceinline__ void stage8s(const char* gslice, int rowstride,
                                        char* ldsslice, int ln) {
#pragma unroll
    for (int i = 0; i < 8; i++)
        gload16(gslice + (size_t)i * rowstride + ln * 16, ldsslice + i * 1024);
}

__device__ __forceinline__ void fma8h(float4& a0, float4& a1, float s, float4 raw) {
    const __half2* hp = (const __half2*)&raw;
    float2 p0 = __half22float2(hp[0]), p1 = __half22float2(hp[1]);
    float2 p2 = __half22float2(hp[2]), p3 = __half22float2(hp[3]);
    a0.x += s * p0.x; a0.y += s * p0.y; a0.z += s * p1.x; a0.w += s * p1.y;
    a1.x += s * p2.x; a1.y += s * p2.y; a1.z += s * p3.x; a1.w += s * p3.y;
}

// Pipelined GEMV, C=512 K=128. Wave w owns K-rows [w*16,w*16+16) staged as two
// 8 KB half-chunks already in flight at entry. While computing each half it
// re-issues the chunk two ahead (next phase's weights) into the same buffer.
// vmcnt<=8 == "everything but the newest 8 loads retired" (in-order retire).
__device__ __forceinline__ void gemv512_pipe(const float* act, float* wbuf,
                                             float* s_part,
                                             const char* nextA, const char* nextB,
                                             int nextStride, int w, int ln) {
    float4 a0 = {0,0,0,0}, a1 = {0,0,0,0};
    const float4* w4 = (const float4*)wbuf;
    wait_vm<8>();
#pragma unroll
    for (int r = 0; r < 8; r++)
        fma8h(a0, a1, act[w * 16 + r], w4[r * 64 + ln]);
    wait_lgkm0(); sbar0();
    if (nextA) { stage8s(nextA, nextStride, (char*)wbuf, ln); wait_vm<8>(); }
    else       { wait_vm<0>(); }
#pragma unroll
    for (int r = 8; r < 16; r++)
        fma8h(a0, a1, act[w * 16 + r], w4[r * 64 + ln]);
    wait_lgkm0(); sbar0();
    if (nextB) stage8s(nextB, nextStride, (char*)wbuf + 8192, ln);
    ((float4*)(s_part + w * 512))[ln * 2]     = a0;
    ((float4*)(s_part + w * 512))[ln * 2 + 1] = a1;
}

// Pipelined GEMV, C=128 K=512. Wave w owns K-rows [w*64,w*64+64) (256 B each),
// two 8 KB half-chunks of 32 rows. Same rolling-window discipline.
__device__ __forceinline__ void gemv128_pipe(const float* act, float* wbuf,
                                             float* s_part,
                                             const char* nextA, const char* nextB,
                                             int nextStride, int w, int ln) {
    float2 acc = {0, 0};
    wait_vm<8>();
#pragma unroll 8
    for (int r = 0; r < 32; r++) {
        float raw = wbuf[r * 64 + ln];
        float2 p = __half22float2(*(const __half2*)&raw);
        float a = act[w * 64 + r];
        acc.x += a * p.x; acc.y += a * p.y;
    }
    wait_lgkm0(); sbar0();
    if (nextA) { stage8s(nextA, nextStride, (char*)wbuf, ln); wait_vm<8>(); }
    else       { wait_vm<0>(); }
#pragma unroll 8
    for (int r = 32; r < 64; r++) {
        float raw = wbuf[r * 64 + ln];
        float2 p = __half22float2(*(const __half2*)&raw);
        float a = act[w * 64 + r];
        acc.x += a * p.x; acc.y += a * p.y;
    }
    wait_lgkm0(); sbar0();
    if (nextB) stage8s(nextB, nextStride, (char*)wbuf + 8192, ln);
    s_part[w * 128 + ln * 2]     = acc.x;
    s_part[w * 128 + ln * 2 + 1] = acc.y;
}

// N-value block reduce (8 waves); results broadcast into vals[].
template <int N>
__device__ __forceinline__ void block_reduce_n(float* vals, float* sbuf) {
#pragma unroll
    for (int off = 32; off > 0; off >>= 1)
#pragma unroll
        for (int q = 0; q < N; q++) vals[q] += __shfl_xor(vals[q], off, 64);
    int wave = threadIdx.x >> 6;
    if ((threadIdx.x & 63) == 0)
#pragma unroll
        for (int q = 0; q < N; q++) sbuf[wave * N + q] = vals[q];
    __syncthreads();
#pragma unroll
    for (int q = 0; q < N; q++) {
        float r = 0.0f;
#pragma unroll
        for (int g = 0; g < 8; g++) r += sbuf[g * N + q];
        vals[q] = r;
    }
    __syncthreads();
}

__device__ __forceinline__ float gelu_exact(float a) {
    return 0.5f * a * (1.0f + erff(a * 0.70710678f));
}

// ---------- kernels ----------

__global__ __launch_bounds__(512) void k_cvt(const float* Wq, const float* Wkv,
                                             const float* Wo, const float* W1,
                                             const float* W2,
                                             __half* hWq, __half* hWkv, __half* hWo,
                                             __half* hW1, __half* hW2,
                                             const float* blin, float* out) {
    if (blockIdx.x == 0 && threadIdx.x == 0) out[0] = 256.0f * blin[0];
    int g = blockIdx.x * 512 + threadIdx.x;
    const float4* src; __half* dst; int off;
    if (g < 98304)       { src = (const float4*)Wq;  dst = hWq;  off = g; }
    else if (g < 294912) { src = (const float4*)Wkv; dst = hWkv; off = g - 98304; }
    else if (g < 393216) { src = (const float4*)Wo;  dst = hWo;  off = g - 294912; }
    else if (g < 491520) { src = (const float4*)W1;  dst = hW1;  off = g - 393216; }
    else                 { src = (const float4*)W2;  dst = hW2;  off = g - 491520; }
    float4 v = src[off];
    __half2* d2 = (__half2*)(dst + (size_t)off * 4);
    d2[0] = __floats2half2_rn(v.x, v.y);
    d2[1] = __floats2half2_rn(v.z, v.w);
}

__global__ __launch_bounds__(512, 1) void k_pre(const int* indices, const float* noise,
                                                const float* atom_emb,
                                                const float* ln1_g, const float* ln1_b,
                                                const __half* hWq, const float* bq,
                                                const __half* hWkv, const float* bkv,
                                                float* nodes, float* qb,
                                                __half* hk, __half* hv) {
    int bn = blockIdx.x;
    int t  = threadIdx.x;
    int d  = t & 127;
    bool own = (t < 128);
    int w = t >> 6, ln = t & 63;
    __shared__ float arena[32768];
    __shared__ float s_xn[128];
    __shared__ float s_red[48];
    __shared__ float s_part[4096];
    char*  lslice = (char*)arena + w * 16384;
    float* wbuf   = arena + w * 4096;

    // stage Wq halves immediately; DMA flies over gather + LN
    const char* WqL  = (const char*)hWq;
    const char* WkvL = (const char*)hWkv;
    stage8s(WqL + w * 16384, 1024, lslice, ln);
    stage8s(WqL + w * 16384 + 8192, 1024, lslice + 8192, ln);

    float nd = 0.0f;
    if (own) {
        int idx = indices[bn];
        nd = (d < NF) ? atom_emb[idx * NF + d] : noise[0];
        nodes[bn * DIMM + d] = nd;
    }
    float vals[2] = {own ? nd : 0.0f, own ? nd * nd : 0.0f};
    block_reduce_n<2>(vals, s_red);
    float m   = vals[0] * (1.0f / 128.0f);
    float var = vals[1] * (1.0f / 128.0f) - m * m;
    if (own) s_xn[d] = (nd - m) * rsqrtf(var + 1e-5f) * ln1_g[d] + ln1_b[d];
    __syncthreads();

    // Wq (stages Wk halves mid-flight)
    gemv512_pipe(s_xn, wbuf, s_part,
                 WkvL + (size_t)(w * 16) * 2048,
                 WkvL + (size_t)(w * 16 + 8) * 2048, 2048, w, ln);
    __syncthreads();
    {
        float q = bq[t];
#pragma unroll
        for (int g = 0; g < 8; g++) q += s_part[g * 512 + t];
        qb[(size_t)bn * INNER + t] = q;
    }
    __syncthreads();

    // Wk (stages Wv halves)
    gemv512_pipe(s_xn, wbuf, s_part,
                 WkvL + (size_t)(w * 16) * 2048 + 1024,
                 WkvL + (size_t)(w * 16 + 8) * 2048 + 1024, 2048, w, ln);
    __syncthreads();
    {
        float k = bkv[t];
#pragma unroll
        for (int g = 0; g < 8; g++) k += s_part[g * 512 + t];
        hk[(size_t)bn * INNER + t] = __float2half(k);
    }
    __syncthreads();

    // Wv (tail)
    gemv512_pipe(s_xn, wbuf, s_part, nullptr, nullptr, 0, w, ln);
    __syncthreads();
    {
        float v = bkv[INNER + t];
#pragma unroll
        for (int g = 0; g < 8; g++) v += s_part[g * 512 + t];
        hv[(size_t)bn * INNER + t] = __float2half(v);
    }
}

__global__ __launch_bounds__(512, 1) void k_layer(int l,
        const float* coords, const int* bonds,
        const float* We, const float* be,
        float* qb, const __half* hkin, const __half* hvin,
        __half* hkout, __half* hvout,
        const __half* hWo, const float* bo, const float* Wg1,
        const float* ln2_g, const float* ln2_b,
        const __half* hW1, const float* b1,
        const __half* hW2, const float* b2,
        const float* Wg2,
        const float* ln1_g, const float* ln1_b,
        const __half* hWq, const float* bq,
        const __half* hWkv, const float* bkv,
        float* nodes, const float* Wlin, float* out) {
    int bn = blockIdx.x;
    int b = bn >> 7, i = bn & 127;
    int t = threadIdx.x;
    int d = t & 127;
    bool own = (t < 128);
    int w = t >> 6, ln = t & 63;

    __shared__ float arena[32768];     // per-wave weight slices (16 KB each)
    __shared__ float scoord[384];
    __shared__ float sedge[384];
    __shared__ int   sadj[128];
    __shared__ float s_l[64];
    __shared__ float s_ao[512];
    __shared__ float s_h[512];
    __shared__ float s_xn[128];
    __shared__ float s_red[48];
    __shared__ float s_part[4096];     // aliased as s_o in attention
    float* s_o = s_part;
    char*  lslice = (char*)arena + w * 16384;
    float* wbuf   = arena + w * 4096;

    const char* WoL  = (const char*)(hWo + (size_t)l * INNER * DIMM);
    const char* W1L  = (const char*)(hW1 + (size_t)l * DIMM * 4 * DIMM);
    const char* W2L  = (const char*)(hW2 + (size_t)l * 4 * DIMM * DIMM);
    const char* WqL  = (const char*)(hWq + (size_t)(l + 1) * DIMM * INNER);
    const char* WkvL = (const char*)(hWkv + (size_t)(l + 1) * DIMM * 2 * INNER);

    // stage Wo halves immediately; DMA flies over the whole attention phase
    stage8s(WoL + w * 16384, 1024, lslice, ln);
    stage8s(WoL + w * 16384 + 8192, 1024, lslice + 8192, ln);

    // ---------- attention: wave w owns j in [w*16, w*16+16); 64 lanes = 512 dims ----------
    const float4* qR4 = (const float4*)(qb + (size_t)bn * INNER);
    const float4* WeR = (const float4*)(We + (size_t)l * 3 * INNER);
    float4 qa  = qR4[ln * 2],        qz  = qR4[ln * 2 + 1];
    float4 w0a = WeR[ln * 2],        w0z = WeR[ln * 2 + 1];
    float4 w1a = WeR[128 + ln * 2],  w1z = WeR[129 + ln * 2];
    float4 w2a = WeR[256 + ln * 2],  w2z = WeR[257 + ln * 2];
    float4 bea = ((const float4*)(be + (size_t)l * INNER))[ln * 2];
    float4 bez = ((const float4*)(be + (size_t)l * INNER))[ln * 2 + 1];
    float res = own ? nodes[bn * DIMM + d] : 0.0f;
    h2f16 qh0 = {(_Float16)qa.x, (_Float16)qa.y};
    h2f16 qh1 = {(_Float16)qa.z, (_Float16)qa.w};
    h2f16 qh2 = {(_Float16)qz.x, (_Float16)qz.y};
    h2f16 qh3 = {(_Float16)qz.z, (_Float16)qz.w};
    // per-head q.be (non-bonded j have e == be exactly)
    float c = qa.x * bea.x + qa.y * bea.y + qa.z * bea.z + qa.w * bea.w
            + qz.x * bez.x + qz.y * bez.y + qz.z * bez.z + qz.w * bez.w;
    c += __shfl_xor(c, 1, 64); c += __shfl_xor(c, 2, 64); c += __shfl_xor(c, 4, 64);

    if (t < 3 * NN) scoord[t] = coords[b * 3 * NN + t];
    if (t < NN) sadj[t] = 0;
    __syncthreads();
    if (t < EE) {
        int e0 = bonds[2 * t], e1 = bonds[2 * t + 1];
        if (e0 == i) sadj[e1] = 1;
        if (e1 == i) sadj[e0] = 1;
    }
    __syncthreads();
    if (t < NN) {
        int j = t;
        float msk = sadj[j] ? 1.0f : 0.0f;
        sedge[3 * j + 0] = msk * (scoord[3 * i + 0] - scoord[3 * j + 0]);
        sedge[3 * j + 1] = msk * (scoord[3 * i + 1] - scoord[3 * j + 1]);
        sedge[3 * j + 2] = msk * (scoord[3 * i + 2] - scoord[3 * j + 2]);
    }
    __syncthreads();

    const float4* kR = (const float4*)(hkin + (size_t)b * NN * INNER);   // 8 halves/elt
    const float4* vR = (const float4*)(hvin + (size_t)b * NN * INNER);
    float l_run = 0.0f, S_nb = 0.0f;
    float4 o0 = {0, 0, 0, 0}, o1 = {0, 0, 0, 0};
    int j0 = w * 16;
#pragma unroll
    for (int base = 0; base < 16; base += 4) {
        float4 kraw[4], vraw[4];
#pragma unroll
        for (int p = 0; p < 4; p++) {
            int j = j0 + base + p;
            kraw[p] = kR[j * 64 + ln];
            vraw[p] = vR[j * 64 + ln];
        }
#pragma unroll
        for (int p = 0; p < 4; p++) {
            int j = j0 + base + p;
            const h2f16* kh = (const h2f16*)&kraw[p];
            float s = fdot2f(qh0, kh[0],
                      fdot2f(qh1, kh[1],
                      fdot2f(qh2, kh[2],
                      fdot2f(qh3, kh[3], 0.0f))));
            bool bonded = (sadj[j] != 0);      // wave-uniform branch
            float4 e0, e1;
            if (bonded) {
                float ex = sedge[3 * j], ey = sedge[3 * j + 1], ez = sedge[3 * j + 2];
                e0.x = bea.x + ex * w0a.x + ey * w1a.x + ez * w2a.x;
                e0.y = bea.y + ex * w0a.y + ey * w1a.y + ez * w2a.y;
                e0.z = bea.z + ex * w0a.z + ey * w1a.z + ez * w2a.z;
                e0.w = bea.w + ex * w0a.w + ey * w1a.w + ez * w2a.w;
                e1.x = bez.x + ex * w0z.x + ey * w1z.x + ez * w2z.x;
                e1.y = bez.y + ex * w0z.y + ey * w1z.y + ez * w2z.y;
                e1.z = bez.z + ex * w0z.z + ey * w1z.z + ez * w2z.z;
                e1.w = bez.w + ex * w0z.w + ey * w1z.w + ez * w2z.w;
                s += qa.x * e0.x + qa.y * e0.y + qa.z * e0.z + qa.w * e0.w
                   + qz.x * e1.x + qz.y * e1.y + qz.z * e1.z + qz.w * e1.w;
            }
            s += __shfl_xor(s, 1, 64);
            s += __shfl_xor(s, 2, 64);
            s += __shfl_xor(s, 4, 64);
            if (!bonded) s += c;
            float pp = __expf(s * 0.125f);
            l_run += pp;
            const __half2* vh = (const __half2*)&vraw[p];
            float2 v0 = __half22float2(vh[0]), v1 = __half22float2(vh[1]);
            float2 v2 = __half22float2(vh[2]), v3 = __half22float2(vh[3]);
            o0.x += pp * v0.x; o0.y += pp * v0.y; o0.z += pp * v1.x; o0.w += pp * v1.y;
            o1.x += pp * v2.x; o1.y += pp * v2.y; o1.z += pp * v3.x; o1.w += pp * v3.y;
            if (bonded) {
                o0.x += pp * e0.x; o0.y += pp * e0.y; o0.z += pp * e0.z; o0.w += pp * e0.w;
                o1.x += pp * e1.x; o1.y += pp * e1.y; o1.z += pp * e1.z; o1.w += pp * e1.w;
            } else S_nb += pp;
        }
    }
    // fold the shared be contribution of all non-bonded j
    o0.x += S_nb * bea.x; o0.y += S_nb * bea.y; o0.z += S_nb * bea.z; o0.w += S_nb * bea.w;
    o1.x += S_nb * bez.x; o1.y += S_nb * bez.y; o1.z += S_nb * bez.z; o1.w += S_nb * bez.w;
    ((float4*)(s_o + w * 512))[ln * 2]     = o0;
    ((float4*)(s_o + w * 512))[ln * 2 + 1] = o1;
    if ((ln & 7) == 0) s_l[w * 8 + (ln >> 3)] = l_run;
    __syncthreads();
    {
        float o = 0.0f;
#pragma unroll
        for (int g = 0; g < 8; g++) o += s_o[g * 512 + t];
        int h = t >> 6;
        float lsum = 0.0f;
#pragma unroll
        for (int g = 0; g < 8; g++) lsum += s_l[g * 8 + h];
        s_ao[t] = o / lsum;
    }
    __syncthreads();

    // ---------- Wo [512 x 128], K-split (stages W1 halves mid-flight) ----------
    gemv128_pipe(s_ao, wbuf, s_part,
                 W1L + w * 16384, W1L + w * 16384 + 8192, 1024, w, ln);
    __syncthreads();
    float x = 0.0f;
    if (own) {
        x = bo[l * DIMM + d];
#pragma unroll
        for (int g = 0; g < 8; g++) x += s_part[g * 128 + d];
    }

    // ---------- fused gate1 + LN2 (single reduce pass) ----------
    const float* Wg1_l = Wg1 + l * 3 * DIMM;
    float n1;
    {
        float tex = own ? (x * Wg1_l[d] + res * Wg1_l[DIMM + d]
                           + (x - res) * Wg1_l[2 * DIMM + d]) : 0.0f;
        float vals[6] = {tex,
                         own ? x : 0.0f, own ? x * x : 0.0f,
                         own ? x * res : 0.0f,
                         own ? res : 0.0f, own ? res * res : 0.0f};
        block_reduce_n<6>(vals, s_red);
        float g1 = 1.0f / (1.0f + __expf(-vals[0]));
        float sn  = g1 * vals[1] + (1.0f - g1) * vals[4];
        float sn2 = g1 * g1 * vals[2] + 2.0f * g1 * (1.0f - g1) * vals[3]
                  + (1.0f - g1) * (1.0f - g1) * vals[5];
        float m   = sn * (1.0f / 128.0f);
        float var = sn2 * (1.0f / 128.0f) - m * m;
        n1 = x * g1 + res * (1.0f - g1);
        if (own) s_xn[d] = (n1 - m) * rsqrtf(var + 1e-5f) * ln2_g[l * DIMM + d]
                         + ln2_b[l * DIMM + d];
    }
    __syncthreads();

    // ---------- W1 [128 x 512] + gelu (stages W2 halves mid-flight) ----------
    gemv512_pipe(s_xn, wbuf, s_part,
                 W2L + w * 16384, W2L + w * 16384 + 8192, 1024, w, ln);
    __syncthreads();
    {
        float a = b1[l * 4 * DIMM + t];
#pragma unroll
        for (int g = 0; g < 8; g++) a += s_part[g * 512 + t];
        s_h[t] = gelu_exact(a);
    }
    __syncthreads();

    // ---------- W2 [512 x 128], K-split (stages next-layer Wq if needed) ----------
    gemv128_pipe(s_h, wbuf, s_part,
                 (l < DEPTH - 1) ? WqL + w * 16384 : nullptr,
                 (l < DEPTH - 1) ? WqL + w * 16384 + 8192 : nullptr, 1024, w, ln);
    __syncthreads();
    float y = 0.0f;
    if (own) {
        y = b2[l * DIMM + d];
#pragma unroll
        for (int g = 0; g < 8; g++) y += s_part[g * 128 + d];
    }

    const float* Wg2_l = Wg2 + l * 3 * DIMM;
    if (l < DEPTH - 1) {
        // ---------- fused gate2 + LN1' (single reduce pass) ----------
        float tex = own ? (y * Wg2_l[d] + n1 * Wg2_l[DIMM + d]
                           + (y - n1) * Wg2_l[2 * DIMM + d]) : 0.0f;
        float vals[6] = {tex,
                         own ? y : 0.0f, own ? y * y : 0.0f,
                         own ? y * n1 : 0.0f,
                         own ? n1 : 0.0f, own ? n1 * n1 : 0.0f};
        block_reduce_n<6>(vals, s_red);
        float g2 = 1.0f / (1.0f + __expf(-vals[0]));
        float sn  = g2 * vals[1] + (1.0f - g2) * vals[4];
        float sn2 = g2 * g2 * vals[2] + 2.0f * g2 * (1.0f - g2) * vals[3]
                  + (1.0f - g2) * (1.0f - g2) * vals[5];
        float m   = sn * (1.0f / 128.0f);
        float var = sn2 * (1.0f / 128.0f) - m * m;
        float n2 = y * g2 + n1 * (1.0f - g2);
        if (own) {
            nodes[bn * DIMM + d] = n2;
            s_xn[d] = (n2 - m) * rsqrtf(var + 1e-5f) * ln1_g[(l + 1) * DIMM + d]
                    + ln1_b[(l + 1) * DIMM + d];
        }
        __syncthreads();

        // Wq (stages Wk halves)
        gemv512_pipe(s_xn, wbuf, s_part,
                     WkvL + (size_t)(w * 16) * 2048,
                     WkvL + (size_t)(w * 16 + 8) * 2048, 2048, w, ln);
        __syncthreads();
        {
            float q = bq[(l + 1) * INNER + t];
#pragma unroll
            for (int g = 0; g < 8; g++) q += s_part[g * 512 + t];
            qb[(size_t)bn * INNER + t] = q;
        }
        __syncthreads();

        // Wk (stages Wv halves)
        gemv512_pipe(s_xn, wbuf, s_part,
                     WkvL + (size_t)(w * 16) * 2048 + 1024,
                     WkvL + (size_t)(w * 16 + 8) * 2048 + 1024, 2048, w, ln);
        __syncthreads();
        {
            float k = bkv[(l + 1) * 2 * INNER + t];
#pragma unroll
            for (int g = 0; g < 8; g++) k += s_part[g * 512 + t];
            hkout[(size_t)bn * INNER + t] = __float2half(k);
        }
        __syncthreads();

        // Wv (tail)
        gemv512_pipe(s_xn, wbuf, s_part, nullptr, nullptr, 0, w, ln);
        __syncthreads();
        {
            float v = bkv[(l + 1) * 2 * INNER + INNER + t];
#pragma unroll
            for (int g = 0; g < 8; g++) v += s_part[g * 512 + t];
            hvout[(size_t)bn * INNER + t] = __float2half(v);
        }
    } else {
        // ---------- fused gate2 + final contribution ----------
        float wl = own ? Wlin[d] : 0.0f;
        float tex = own ? (y * Wg2_l[d] + n1 * Wg2_l[DIMM + d]
                           + (y - n1) * Wg2_l[2 * DIMM + d]) : 0.0f;
        float vals[3] = {tex, y * wl, n1 * wl};
        block_reduce_n<3>(vals, s_red);
        float g2 = 1.0f / (1.0f + __expf(-vals[0]));
        float tot = g2 * vals[1] + (1.0f - g2) * vals[2];
        if (t == 0) atomicAdd(out, tot);
    }
}

extern "C" void kernel_launch(void* const* d_in, const int* in_sizes, int n_in,
                              void* d_out, int out_size, void* d_ws, size_t ws_size,
                              hipStream_t stream) {
    const int*   indices = (const int*)d_in[0];
    const float* coords  = (const float*)d_in[1];
    const int*   bonds   = (const int*)d_in[2];
    const float* noise   = (const float*)d_in[3];
    const float* atom_emb= (const float*)d_in[4];
    const float* ln1_g   = (const float*)d_in[5];
    const float* ln1_b   = (const float*)d_in[6];
    const float* Wq      = (const float*)d_in[7];
    const float* bq      = (const float*)d_in[8];
    const float* Wkv     = (const float*)d_in[9];
    const float* bkv     = (const float*)d_in[10];
    const float* We      = (const float*)d_in[11];
    const float* be      = (const float*)d_in[12];
    const float* Wo      = (const float*)d_in[13];
    const float* bo      = (const float*)d_in[14];
    const float* Wg1     = (const float*)d_in[15];
    const float* ln2_g   = (const float*)d_in[16];
    const float* ln2_b   = (const float*)d_in[17];
    const float* W1      = (const float*)d_in[18];
    const float* b1      = (const float*)d_in[19];
    const float* W2      = (const float*)d_in[20];
    const float* b2      = (const float*)d_in[21];
    const float* Wg2     = (const float*)d_in[22];
    const float* Wlin    = (const float*)d_in[23];
    const float* blin    = (const float*)d_in[24];

    float*  ws    = (float*)d_ws;
    float*  nodes = ws;                         // 32768 f
    float*  qb    = nodes + NNODE * DIMM;       // 131072 f
    __half* hkb   = (__half*)(qb + NNODE * INNER);  // 2 slabs x 131072 halves
    __half* hvb   = hkb + 2 * NNODE * INNER;
    __half* hWq   = hvb + 2 * NNODE * INNER;
    __half* hWkv  = hWq + DEPTH * DIMM * INNER;
    __half* hWo   = hWkv + DEPTH * DIMM * 2 * INNER;
    __half* hW1   = hWo + DEPTH * INNER * DIMM;
    __half* hW2   = hW1 + DEPTH * DIMM * 4 * DIMM;

    k_cvt<<<1152, 512, 0, stream>>>(Wq, Wkv, Wo, W1, W2, hWq, hWkv, hWo, hW1, hW2,
                                    blin, (float*)d_out);
    k_pre<<<NNODE, 512, 0, stream>>>(indices, noise, atom_emb, ln1_g, ln1_b,
                                     hWq, bq, hWkv, bkv, nodes, qb, hkb, hvb);
    for (int l = 0; l < DEPTH; l++) {
        const __half* hkin = hkb + (size_t)(l & 1) * NNODE * INNER;
        const __half* hvin = hvb + (size_t)(l & 1) * NNODE * INNER;
        __half* hkout = hkb + (size_t)((l + 1) & 1) * NNODE * INNER;
        __half* hvout = hvb + (size_t)((l + 1) & 1) * NNODE * INNER;
        k_layer<<<NNODE, 512, 0, stream>>>(l, coords, bonds, We, be,
                                           qb, hkin, hvin, hkout, hvout,
                                           hWo, bo, Wg1, ln2_g, ln2_b, hW1, b1, hW2, b2,
                                           Wg2, ln1_g, ln1_b, hWq, bq, hWkv, bkv,
                                           nodes, Wlin, (float*)d_out);
    }
}